// Round 6
// baseline (443.117 us; speedup 1.0000x reference)
//
#include <hip/hip_runtime.h>
#include <hip/hip_bf16.h>

#define BB 64
#define TT 1024
#define CHN 256
#define VV 32000
#define EE 64
#define LL 128
#define NC1 250      // k1 k-chunks (250*128 = 32000)
#define KC1 128
#define TS 16        // attention t-chunks (64 t each)

typedef unsigned short u16;
typedef unsigned int u32;

__device__ __forceinline__ float fast_rcp(float x) { return __builtin_amdgcn_rcpf(x); }
__device__ __forceinline__ float tanh_fast(float y) {
    float e = __expf(2.0f * y);              // inf/0 limits give +-1 correctly
    return 1.0f - 2.0f * fast_rcp(1.0f + e);
}
__device__ __forceinline__ float sigmoid_fast(float x) {
    return fast_rcp(1.0f + __expf(-x));
}

// ---------------- K1: prev_char[64,32000] @ Wc[32000,64] -> part[b][kc][e] -----------
// grid (250 kc, 2 bhalf) x 256 thr. lane=e; wave=8 b. 8-deep double-buffered Wc
// prefetch keeps 8 independent global loads in flight during every FMA block.
__global__ __launch_bounds__(256) void k1_stage1(const float* __restrict__ A,
                                                 const float* __restrict__ Wc,
                                                 float* __restrict__ part) {
    const int kc = blockIdx.x;
    const int k0 = kc * KC1;
    const int e  = threadIdx.x & 63;
    const int b0 = blockIdx.y * 32 + __builtin_amdgcn_readfirstlane(threadIdx.x >> 6) * 8;

    float acc[8];
    #pragma unroll
    for (int i = 0; i < 8; ++i) acc[i] = 0.0f;

    const float* W  = Wc + (size_t)k0 * EE + e;
    const float* Ar = A + (size_t)b0 * VV + k0;           // wave-uniform base
    float wa[8], wb[8];
    #pragma unroll
    for (int j = 0; j < 8; ++j) wa[j] = W[(size_t)j * EE];

    for (int k = 0; k < KC1; k += 16) {
        #pragma unroll
        for (int j = 0; j < 8; ++j) wb[j] = W[(size_t)(k + 8 + j) * EE];
        #pragma unroll
        for (int j = 0; j < 8; ++j) {
            #pragma unroll
            for (int i = 0; i < 8; ++i)
                acc[i] = fmaf(Ar[(size_t)i * VV + k + j], wa[j], acc[i]);   // s_load
        }
        if (k + 16 < KC1) {
            #pragma unroll
            for (int j = 0; j < 8; ++j) wa[j] = W[(size_t)(k + 16 + j) * EE];
        }
        #pragma unroll
        for (int j = 0; j < 8; ++j) {
            #pragma unroll
            for (int i = 0; i < 8; ++i)
                acc[i] = fmaf(Ar[(size_t)i * VV + k + 8 + j], wb[j], acc[i]);
        }
    }
    #pragma unroll
    for (int i = 0; i < 8; ++i)
        part[((size_t)(b0 + i) * NC1 + kc) * EE + e] = acc[i];
}

// ---------------- K2: reduce part + pcv@Wct1, z-GEMM, gates, H_tfm -------------------
__global__ __launch_bounds__(512) void k2_lstm(const float* __restrict__ part,
    const float* __restrict__ pcv, const float* __restrict__ state_h,
    const float* __restrict__ state_c, const float* __restrict__ Wct1,
    const float* __restrict__ lstm_kernel, const float* __restrict__ lstm_rec,
    const float* __restrict__ W_h,
    float* __restrict__ out_newh, float* __restrict__ out_newc,
    float* __restrict__ At, float* __restrict__ Htfm) {
    __shared__ float red[8][EE];
    __shared__ float inp[EE];
    __shared__ float sh[LL];
    __shared__ float z[4 * LL];
    __shared__ float nh[LL];
    const int b = blockIdx.x;
    const int t = threadIdx.x;
    const int e  = t & 63;
    const int g  = t >> 6;          // 0..7

    {
        float s = 0.0f;
        for (int j = g; j < NC1; j += 8)                       // contiguous 64KB window
            s += part[((size_t)b * NC1 + j) * EE + e];
        const int c0 = g * 32;
        #pragma unroll 8
        for (int c = 0; c < 32; ++c)
            s = fmaf(pcv[b * CHN + c0 + c], Wct1[(size_t)(c0 + c) * EE + e], s);
        red[g][e] = s;
    }
    __syncthreads();
    if (t < EE) {
        float s = 0.0f;
        #pragma unroll
        for (int j = 0; j < 8; ++j) s += red[j][t];
        inp[t] = s;
    } else if (t >= 64 && t < 64 + LL) {
        sh[t - 64] = state_h[b * LL + (t - 64)];
    }
    __syncthreads();
    {
        float a = 0.0f;
        #pragma unroll 8
        for (int e2 = 0; e2 < EE; ++e2) a = fmaf(inp[e2], lstm_kernel[e2 * 512 + t], a);
        #pragma unroll 8
        for (int l = 0; l < LL; ++l) a = fmaf(sh[l], lstm_rec[l * 512 + t], a);
        z[t] = a;
    }
    __syncthreads();
    if (t < LL) {
        float zi = z[t], zf = z[LL + t], zg = z[2 * LL + t], zo = z[3 * LL + t];
        float ig = sigmoid_fast(zi);
        float fg = sigmoid_fast(zf);
        float gg = tanh_fast(zg);
        float og = sigmoid_fast(zo);
        float co = state_c[b * LL + t];
        float cn = fg * co + ig * gg;
        float hn = og * tanh_fast(cn);
        out_newc[b * LL + t] = fminf(fmaxf(cn, -10.0f), 10.0f);
        out_newh[b * LL + t] = hn;
        At[t * BB + b] = hn;           // At[k][b] layout for k5 scalar reads
        nh[t] = hn;
    }
    __syncthreads();
    if (t < CHN) {
        float a = 0.0f;
        #pragma unroll 8
        for (int l = 0; l < LL; ++l) a = fmaf(nh[l], W_h[l * CHN + t], a);
        Htfm[b * CHN + t] = a;
    }
}

// ---------------- K3: attention partials per (b, ts); double-buffered F stream -------
__global__ __launch_bounds__(256) void k3_attn(const float* __restrict__ F,
    const float* __restrict__ Htfm, const float* __restrict__ Vattn,
    float* __restrict__ pS, float* __restrict__ pW) {
    __shared__ float4 sS[256];
    __shared__ float4 sW[256];
    const int b    = blockIdx.x;
    const int ts   = blockIdx.y;
    const int lane = threadIdx.x & 63;
    const int w    = threadIdx.x >> 6;
    const int ch   = lane * 4;

    float4 h = *(const float4*)(Htfm + b * CHN + ch);
    float4 v = *(const float4*)(Vattn + ch);
    float s0 = 0, s1 = 0, s2 = 0, s3 = 0;
    float a0 = 0, a1 = 0, a2 = 0, a3 = 0;

    const float* Fp = F + ((size_t)b * TT + ts * (TT / TS) + w * 16) * CHN + ch;
    float4 cur = *(const float4*)(Fp);
    #pragma unroll
    for (int t = 0; t < 16; ++t) {
        float4 nxt;
        if (t < 15) nxt = *(const float4*)(Fp + (size_t)(t + 1) * CHN);
        float e0 = __expf(v.x * tanh_fast(h.x + cur.x));
        float e1 = __expf(v.y * tanh_fast(h.y + cur.y));
        float e2 = __expf(v.z * tanh_fast(h.z + cur.z));
        float e3 = __expf(v.w * tanh_fast(h.w + cur.w));
        s0 += e0; s1 += e1; s2 += e2; s3 += e3;
        a0 = fmaf(e0, cur.x, a0); a1 = fmaf(e1, cur.y, a1);
        a2 = fmaf(e2, cur.z, a2); a3 = fmaf(e3, cur.w, a3);
        cur = nxt;
    }
    sS[threadIdx.x] = make_float4(s0, s1, s2, s3);
    sW[threadIdx.x] = make_float4(a0, a1, a2, a3);
    __syncthreads();
    if (threadIdx.x < 64) {
        float4 S = sS[threadIdx.x];
        float4 W = sW[threadIdx.x];
        #pragma unroll
        for (int j = 1; j < 4; ++j) {
            float4 s = sS[j * 64 + threadIdx.x];
            float4 q = sW[j * 64 + threadIdx.x];
            S.x += s.x; S.y += s.y; S.z += s.z; S.w += s.w;
            W.x += q.x; W.y += q.y; W.z += q.z; W.w += q.w;
        }
        int base = (b * TS + ts) * CHN + threadIdx.x * 4;
        *(float4*)(pS + base) = S;
        *(float4*)(pW + base) = W;
    }
}

// ---------------- K4: reduce TS chunks -> c_t; also zeroes rowsum --------------------
__global__ __launch_bounds__(256) void k4_combine(const float* __restrict__ pS,
    const float* __restrict__ pW, float* __restrict__ out_ct, float* __restrict__ At,
    float* __restrict__ rowsum) {
    const int b = blockIdx.x;
    const int ch = threadIdx.x;
    float S = 0.0f, W = 0.0f;
    #pragma unroll
    for (int j = 0; j < TS; ++j) {
        int idx = (b * TS + j) * CHN + ch;
        S += pS[idx];
        W += pW[idx];
    }
    float c = W / S;
    out_ct[b * CHN + ch] = c;
    At[(LL + ch) * BB + b] = c;
    if (b == 0 && ch < BB) rowsum[ch] = 0.0f;   // k5's atomic target (runs later)
}

// ---------------- K5 helper: software-pipelined GEMV phase ---------------------------
__device__ __forceinline__ void k5_phase(const float* __restrict__ W, int kn,
    const float* __restrict__ Abase, float acc[8]) {
    float wa[8], wb[8];
    #pragma unroll
    for (int j = 0; j < 8; ++j) wa[j] = W[(size_t)j * VV];
    for (int k = 0; k < kn; k += 16) {
        #pragma unroll
        for (int j = 0; j < 8; ++j) wb[j] = W[(size_t)(k + 8 + j) * VV];
        #pragma unroll
        for (int j = 0; j < 8; ++j) {
            const float* a = Abase + (size_t)(k + j) * BB;       // s_load x8
            #pragma unroll
            for (int i = 0; i < 8; ++i) acc[i] = fmaf(a[i], wa[j], acc[i]);
        }
        if (k + 16 < kn) {
            #pragma unroll
            for (int j = 0; j < 8; ++j) wa[j] = W[(size_t)(k + 16 + j) * VV];
        }
        #pragma unroll
        for (int j = 0; j < 8; ++j) {
            const float* a = Abase + (size_t)(k + 8 + j) * BB;
            #pragma unroll
            for (int i = 0; i < 8; ++i) acc[i] = fmaf(a[i], wb[j], acc[i]);
        }
    }
}

// ---------------- K5: exp(logits) + per-row partial sums (fused) ---------------------
// 500 blocks x 8 waves; wave w covers b = w*8..w*8+7, all 64 b per block (max weight
// reuse). Stores exp(logit); butterfly-reduces exp over lanes; 8 atomicAdds per wave.
__global__ __launch_bounds__(512) void k5_logits(const float* __restrict__ Wo,
    const float* __restrict__ Wct2, const float* __restrict__ At,
    float* __restrict__ outO, float* __restrict__ rowsum) {
    const int lane = threadIdx.x & 63;
    const int v  = blockIdx.x * 64 + lane;
    const int b0 = __builtin_amdgcn_readfirstlane(threadIdx.x >> 6) * 8;
    float acc[8];
    #pragma unroll
    for (int i = 0; i < 8; ++i) acc[i] = 0.0f;

    k5_phase(Wo + v, LL, At + b0, acc);
    k5_phase(Wct2 + v, CHN, At + (size_t)LL * BB + b0, acc);

    float ex[8];
    #pragma unroll
    for (int i = 0; i < 8; ++i) {
        ex[i] = __expf(acc[i]);                      // logits bounded ~|4| -> safe
        outO[(size_t)(b0 + i) * VV + v] = ex[i];
    }
    // wave-wide sum of ex[i] across 64 lanes
    #pragma unroll
    for (int i = 0; i < 8; ++i) {
        float s = ex[i];
        #pragma unroll
        for (int m = 32; m > 0; m >>= 1) s += __shfl_xor(s, m);
        ex[i] = s;
    }
    if (lane == 0) {
        #pragma unroll
        for (int i = 0; i < 8; ++i) atomicAdd(&rowsum[b0 + i], ex[i]);
    }
}

// ---------------- K5c: normalize: out = exp_stored / rowsum[row] ---------------------
__global__ __launch_bounds__(256) void k5c_norm(float* __restrict__ O,
                                                const float* __restrict__ rowsum) {
    const int gid = blockIdx.x * 256 + threadIdx.x;      // 512000 float4's
    float4* O4 = (float4*)O;
    const u32 row = ((u32)gid * 4u) / (u32)VV;
    const float inv = fast_rcp(rowsum[row]);
    float4 f = O4[gid];
    f.x *= inv; f.y *= inv; f.z *= inv; f.w *= inv;
    O4[gid] = f;
}

extern "C" void kernel_launch(void* const* d_in, const int* in_sizes, int n_in,
                              void* d_out, int out_size, void* d_ws, size_t ws_size,
                              hipStream_t stream) {
    (void)in_sizes; (void)n_in; (void)out_size; (void)ws_size;
    const float* pcv       = (const float*)d_in[0];
    const float* F         = (const float*)d_in[1];
    const float* prev_char = (const float*)d_in[2];
    const float* state_h   = (const float*)d_in[3];
    const float* state_c   = (const float*)d_in[4];
    const float* Wc        = (const float*)d_in[5];
    const float* Wct1      = (const float*)d_in[6];
    const float* Wo        = (const float*)d_in[7];
    const float* Wct2      = (const float*)d_in[8];
    const float* lstm_k    = (const float*)d_in[9];
    const float* lstm_r    = (const float*)d_in[10];
    const float* W_h       = (const float*)d_in[11];
    const float* Vattn     = (const float*)d_in[12];

    // outputs: float32, concatenated flat in return order
    float* outO  = (float*)d_out;                  // [64][32000]
    float* outCt = outO + (size_t)BB * VV;         // [64][256]
    float* outH  = outCt + (size_t)BB * CHN;       // [64][128]
    float* outC  = outH + (size_t)BB * LL;         // [64][128]

    float* ws     = (float*)d_ws;
    float* part   = ws;                            // 250*4096 = 1,024,000 f
    float* pS     = part + (size_t)NC1 * BB * EE;  // 64*16*256 = 262,144 f
    float* pW     = pS + (size_t)BB * TS * CHN;    // 262,144 f
    float* At     = pW + (size_t)BB * TS * CHN;    // 384*64   = 24,576 f
    float* Htfm   = At + (LL + CHN) * BB;          // 16,384 f
    float* rowsum = part;                          // aliases dead part[0..63] after k2

    hipLaunchKernelGGL(k1_stage1, dim3(NC1, 2), dim3(256), 0, stream, prev_char, Wc, part);
    hipLaunchKernelGGL(k2_lstm, dim3(BB), dim3(512), 0, stream, part, pcv, state_h,
                       state_c, Wct1, lstm_k, lstm_r, W_h, outH, outC, At, Htfm);
    hipLaunchKernelGGL(k3_attn, dim3(BB, TS), dim3(256), 0, stream, F, Htfm, Vattn, pS, pW);
    hipLaunchKernelGGL(k4_combine, dim3(BB), dim3(256), 0, stream, pS, pW, outCt, At, rowsum);
    hipLaunchKernelGGL(k5_logits, dim3(VV / 64), dim3(512), 0, stream, Wo, Wct2, At, outO, rowsum);
    hipLaunchKernelGGL(k5c_norm, dim3((BB * VV / 4) / 256), dim3(256), 0, stream, outO, rowsum);
}

// Round 7
// 251.272 us; speedup vs baseline: 1.7635x; 1.7635x over previous
//
#include <hip/hip_runtime.h>
#include <hip/hip_bf16.h>

#define BB 64
#define TT 1024
#define CHN 256
#define VV 32000
#define EE 64
#define LL 128
#define NC1 250      // k1 k-chunks (250*128 = 32000)
#define KC1 128
#define TS 16        // attention t-chunks (64 t each)

typedef unsigned short u16;
typedef unsigned int u32;

__device__ __forceinline__ float fast_rcp(float x) { return __builtin_amdgcn_rcpf(x); }
__device__ __forceinline__ float tanh_fast(float y) {
    float e = __expf(2.0f * y);              // inf/0 limits give +-1 correctly
    return 1.0f - 2.0f * fast_rcp(1.0f + e);
}
__device__ __forceinline__ float sigmoid_fast(float x) {
    return fast_rcp(1.0f + __expf(-x));
}

// ---------------- K1: prev_char[64,32000] @ Wc[32000,64] -> part[b][kc][e] -----------
// grid (250 kc, 2 bhalf) x 256 thr. All operands staged in LDS: Wc chunk 32 KB,
// A chunk transposed 16 KB. Compute: lane=e, wave=8 b; A via uniform ds broadcast.
__global__ __launch_bounds__(256) void k1_stage1(const float* __restrict__ A,
                                                 const float* __restrict__ Wc,
                                                 float* __restrict__ part) {
    __shared__ float sW[KC1][EE];      // 32 KB
    __shared__ float sAT[KC1][32];     // 16 KB, transposed: [k][local_b]
    const int kc = blockIdx.x;
    const int k0 = kc * KC1;
    const int y  = blockIdx.y;
    const int t  = threadIdx.x;

    // stage Wc chunk: 8192 contiguous floats
    #pragma unroll
    for (int f = t; f < 2048; f += 256)
        *(float4*)(&sW[0][0] + f * 4) = *(const float4*)(Wc + (size_t)k0 * EE + f * 4);
    // stage A chunk transposed: thread -> (b_local, 16-k strip)
    {
        const int bl = t & 31;
        const int kq = t >> 5;         // 0..7
        const float* src = A + (size_t)(y * 32 + bl) * VV + k0 + kq * 16;
        #pragma unroll
        for (int j4 = 0; j4 < 4; ++j4) {
            float4 v = *(const float4*)(src + j4 * 4);
            sAT[kq * 16 + j4 * 4 + 0][bl] = v.x;
            sAT[kq * 16 + j4 * 4 + 1][bl] = v.y;
            sAT[kq * 16 + j4 * 4 + 2][bl] = v.z;
            sAT[kq * 16 + j4 * 4 + 3][bl] = v.w;
        }
    }
    __syncthreads();

    const int e  = t & 63;
    const int b0 = (t >> 6) * 8;       // local b of this wave
    float acc[8];
    #pragma unroll
    for (int i = 0; i < 8; ++i) acc[i] = 0.0f;

    #pragma unroll 4
    for (int k = 0; k < KC1; ++k) {
        float wt = sW[k][e];                               // 2-way bank alias = free
        float4 a0 = *(const float4*)&sAT[k][b0];           // uniform -> broadcast
        float4 a1 = *(const float4*)&sAT[k][b0 + 4];
        acc[0] = fmaf(a0.x, wt, acc[0]);
        acc[1] = fmaf(a0.y, wt, acc[1]);
        acc[2] = fmaf(a0.z, wt, acc[2]);
        acc[3] = fmaf(a0.w, wt, acc[3]);
        acc[4] = fmaf(a1.x, wt, acc[4]);
        acc[5] = fmaf(a1.y, wt, acc[5]);
        acc[6] = fmaf(a1.z, wt, acc[6]);
        acc[7] = fmaf(a1.w, wt, acc[7]);
    }
    const int gb = y * 32 + b0;
    #pragma unroll
    for (int i = 0; i < 8; ++i)
        part[((size_t)(gb + i) * NC1 + kc) * EE + e] = acc[i];
}

// ---------------- K2: reduce part + pcv@Wct1, z-GEMM, gates, H_tfm -------------------
__global__ __launch_bounds__(512) void k2_lstm(const float* __restrict__ part,
    const float* __restrict__ pcv, const float* __restrict__ state_h,
    const float* __restrict__ state_c, const float* __restrict__ Wct1,
    const float* __restrict__ lstm_kernel, const float* __restrict__ lstm_rec,
    const float* __restrict__ W_h,
    float* __restrict__ out_newh, float* __restrict__ out_newc,
    float* __restrict__ At, float* __restrict__ Htfm) {
    __shared__ float red[8][EE];
    __shared__ float inp[EE];
    __shared__ float sh[LL];
    __shared__ float z[4 * LL];
    __shared__ float nh[LL];
    const int b = blockIdx.x;
    const int t = threadIdx.x;
    const int e  = t & 63;
    const int g  = t >> 6;          // 0..7

    {
        float s = 0.0f;
        for (int j = g; j < NC1; j += 8)                       // contiguous 64KB window
            s += part[((size_t)b * NC1 + j) * EE + e];
        const int c0 = g * 32;
        #pragma unroll 8
        for (int c = 0; c < 32; ++c)
            s = fmaf(pcv[b * CHN + c0 + c], Wct1[(size_t)(c0 + c) * EE + e], s);
        red[g][e] = s;
    }
    __syncthreads();
    if (t < EE) {
        float s = 0.0f;
        #pragma unroll
        for (int j = 0; j < 8; ++j) s += red[j][t];
        inp[t] = s;
    } else if (t >= 64 && t < 64 + LL) {
        sh[t - 64] = state_h[b * LL + (t - 64)];
    }
    __syncthreads();
    {
        float a = 0.0f;
        #pragma unroll 8
        for (int e2 = 0; e2 < EE; ++e2) a = fmaf(inp[e2], lstm_kernel[e2 * 512 + t], a);
        #pragma unroll 8
        for (int l = 0; l < LL; ++l) a = fmaf(sh[l], lstm_rec[l * 512 + t], a);
        z[t] = a;
    }
    __syncthreads();
    if (t < LL) {
        float zi = z[t], zf = z[LL + t], zg = z[2 * LL + t], zo = z[3 * LL + t];
        float ig = sigmoid_fast(zi);
        float fg = sigmoid_fast(zf);
        float gg = tanh_fast(zg);
        float og = sigmoid_fast(zo);
        float co = state_c[b * LL + t];
        float cn = fg * co + ig * gg;
        float hn = og * tanh_fast(cn);
        out_newc[b * LL + t] = fminf(fmaxf(cn, -10.0f), 10.0f);
        out_newh[b * LL + t] = hn;
        At[t * BB + b] = hn;           // At[k][b] layout for k5
        nh[t] = hn;
    }
    __syncthreads();
    if (t < CHN) {
        float a = 0.0f;
        #pragma unroll 8
        for (int l = 0; l < LL; ++l) a = fmaf(nh[l], W_h[l * CHN + t], a);
        Htfm[b * CHN + t] = a;
    }
}

// ---------------- K3: attention partials per (b, ts); double-buffered F stream -------
__global__ __launch_bounds__(256) void k3_attn(const float* __restrict__ F,
    const float* __restrict__ Htfm, const float* __restrict__ Vattn,
    float* __restrict__ pS, float* __restrict__ pW) {
    __shared__ float4 sS[256];
    __shared__ float4 sW[256];
    const int b    = blockIdx.x;
    const int ts   = blockIdx.y;
    const int lane = threadIdx.x & 63;
    const int w    = threadIdx.x >> 6;
    const int ch   = lane * 4;

    float4 h = *(const float4*)(Htfm + b * CHN + ch);
    float4 v = *(const float4*)(Vattn + ch);
    float s0 = 0, s1 = 0, s2 = 0, s3 = 0;
    float a0 = 0, a1 = 0, a2 = 0, a3 = 0;

    const float* Fp = F + ((size_t)b * TT + ts * (TT / TS) + w * 16) * CHN + ch;
    float4 cur = *(const float4*)(Fp);
    #pragma unroll
    for (int t = 0; t < 16; ++t) {
        float4 nxt;
        if (t < 15) nxt = *(const float4*)(Fp + (size_t)(t + 1) * CHN);
        float e0 = __expf(v.x * tanh_fast(h.x + cur.x));
        float e1 = __expf(v.y * tanh_fast(h.y + cur.y));
        float e2 = __expf(v.z * tanh_fast(h.z + cur.z));
        float e3 = __expf(v.w * tanh_fast(h.w + cur.w));
        s0 += e0; s1 += e1; s2 += e2; s3 += e3;
        a0 = fmaf(e0, cur.x, a0); a1 = fmaf(e1, cur.y, a1);
        a2 = fmaf(e2, cur.z, a2); a3 = fmaf(e3, cur.w, a3);
        cur = nxt;
    }
    sS[threadIdx.x] = make_float4(s0, s1, s2, s3);
    sW[threadIdx.x] = make_float4(a0, a1, a2, a3);
    __syncthreads();
    if (threadIdx.x < 64) {
        float4 S = sS[threadIdx.x];
        float4 W = sW[threadIdx.x];
        #pragma unroll
        for (int j = 1; j < 4; ++j) {
            float4 s = sS[j * 64 + threadIdx.x];
            float4 q = sW[j * 64 + threadIdx.x];
            S.x += s.x; S.y += s.y; S.z += s.z; S.w += s.w;
            W.x += q.x; W.y += q.y; W.z += q.z; W.w += q.w;
        }
        int base = (b * TS + ts) * CHN + threadIdx.x * 4;
        *(float4*)(pS + base) = S;
        *(float4*)(pW + base) = W;
    }
}

// ---------------- K4: reduce TS chunks -> c_t; also zeroes rowsum --------------------
__global__ __launch_bounds__(256) void k4_combine(const float* __restrict__ pS,
    const float* __restrict__ pW, float* __restrict__ out_ct, float* __restrict__ At,
    float* __restrict__ rowsum) {
    const int b = blockIdx.x;
    const int ch = threadIdx.x;
    float S = 0.0f, W = 0.0f;
    #pragma unroll
    for (int j = 0; j < TS; ++j) {
        int idx = (b * TS + j) * CHN + ch;
        S += pS[idx];
        W += pW[idx];
    }
    float c = W / S;
    out_ct[b * CHN + ch] = c;
    At[(LL + ch) * BB + b] = c;
    if (b == 0 && ch < BB) rowsum[ch] = 0.0f;   // k5b's atomic target (runs later)
}

// ---------------- K5 phase: float2 weights (4-deep dbuf) x LDS-broadcast A -----------
// sAt points into LDS at [k=0][w8]; advances 32 floats per k.
__device__ __forceinline__ void k5_phase(const float* __restrict__ W, int kn,
    const float* sAt, float2 acc[8]) {
    float2 wa[4], wb[4];
    #pragma unroll
    for (int j = 0; j < 4; ++j) wa[j] = *(const float2*)(W + (size_t)j * VV);
    for (int k = 0; k < kn; k += 8) {
        #pragma unroll
        for (int j = 0; j < 4; ++j) wb[j] = *(const float2*)(W + (size_t)(k + 4 + j) * VV);
        #pragma unroll
        for (int j = 0; j < 4; ++j) {
            const float* a = sAt + (size_t)(k + j) * 32;
            float4 x = *(const float4*)a;             // uniform ds_read_b128 broadcast
            float4 z = *(const float4*)(a + 4);
            acc[0].x = fmaf(x.x, wa[j].x, acc[0].x); acc[0].y = fmaf(x.x, wa[j].y, acc[0].y);
            acc[1].x = fmaf(x.y, wa[j].x, acc[1].x); acc[1].y = fmaf(x.y, wa[j].y, acc[1].y);
            acc[2].x = fmaf(x.z, wa[j].x, acc[2].x); acc[2].y = fmaf(x.z, wa[j].y, acc[2].y);
            acc[3].x = fmaf(x.w, wa[j].x, acc[3].x); acc[3].y = fmaf(x.w, wa[j].y, acc[3].y);
            acc[4].x = fmaf(z.x, wa[j].x, acc[4].x); acc[4].y = fmaf(z.x, wa[j].y, acc[4].y);
            acc[5].x = fmaf(z.y, wa[j].x, acc[5].x); acc[5].y = fmaf(z.y, wa[j].y, acc[5].y);
            acc[6].x = fmaf(z.z, wa[j].x, acc[6].x); acc[6].y = fmaf(z.z, wa[j].y, acc[6].y);
            acc[7].x = fmaf(z.w, wa[j].x, acc[7].x); acc[7].y = fmaf(z.w, wa[j].y, acc[7].y);
        }
        if (k + 8 < kn) {
            #pragma unroll
            for (int j = 0; j < 4; ++j) wa[j] = *(const float2*)(W + (size_t)(k + 8 + j) * VV);
        }
        #pragma unroll
        for (int j = 0; j < 4; ++j) {
            const float* a = sAt + (size_t)(k + 4 + j) * 32;
            float4 x = *(const float4*)a;
            float4 z = *(const float4*)(a + 4);
            acc[0].x = fmaf(x.x, wb[j].x, acc[0].x); acc[0].y = fmaf(x.x, wb[j].y, acc[0].y);
            acc[1].x = fmaf(x.y, wb[j].x, acc[1].x); acc[1].y = fmaf(x.y, wb[j].y, acc[1].y);
            acc[2].x = fmaf(x.z, wb[j].x, acc[2].x); acc[2].y = fmaf(x.z, wb[j].y, acc[2].y);
            acc[3].x = fmaf(x.w, wb[j].x, acc[3].x); acc[3].y = fmaf(x.w, wb[j].y, acc[3].y);
            acc[4].x = fmaf(z.x, wb[j].x, acc[4].x); acc[4].y = fmaf(z.x, wb[j].y, acc[4].y);
            acc[5].x = fmaf(z.y, wb[j].x, acc[5].x); acc[5].y = fmaf(z.y, wb[j].y, acc[5].y);
            acc[6].x = fmaf(z.z, wb[j].x, acc[6].x); acc[6].y = fmaf(z.z, wb[j].y, acc[6].y);
            acc[7].x = fmaf(z.w, wb[j].x, acc[7].x); acc[7].y = fmaf(z.w, wb[j].y, acc[7].y);
        }
    }
}

// ---------------- K5: exp(logits) into O region (no atomics) -------------------------
// grid (250 v-tiles, 2 b-halves) x 256 thr = 2000 waves. At slice (384x32=48KB) in LDS.
__global__ __launch_bounds__(256) void k5_logits(const float* __restrict__ Wo,
    const float* __restrict__ Wct2, const float* __restrict__ At,
    float* __restrict__ outO) {
    __shared__ float sAt[384][32];     // 48 KB
    const int y = blockIdx.y;
    const int t = threadIdx.x;

    // stage At cols [y*32, y*32+32) for all 384 k
    #pragma unroll
    for (int f = t; f < 3072; f += 256) {         // 3072 float4 = 12288 floats
        int k  = f >> 3;
        int c4 = (f & 7) * 4;
        *(float4*)&sAt[k][c4] = *(const float4*)(At + (size_t)k * BB + y * 32 + c4);
    }
    __syncthreads();

    const int lane = t & 63;
    const int v2   = blockIdx.x * 128 + lane * 2;
    const int w8   = (t >> 6) * 8;                // local b of this wave
    float2 acc[8];
    #pragma unroll
    for (int i = 0; i < 8; ++i) acc[i] = make_float2(0.0f, 0.0f);

    k5_phase(Wo + v2, LL, &sAt[0][0] + w8, acc);
    k5_phase(Wct2 + v2, CHN, &sAt[LL][0] + w8, acc);

    const int gb = y * 32 + w8;
    #pragma unroll
    for (int i = 0; i < 8; ++i) {
        float2 ex = make_float2(__expf(acc[i].x), __expf(acc[i].y));  // logits bounded
        *(float2*)(outO + (size_t)(gb + i) * VV + v2) = ex;
    }
}

// ---------------- K5b: per-row-chunk sum of stored exp -> atomic rowsum[64] ----------
__global__ __launch_bounds__(256) void k5b_expsum(const float* __restrict__ O,
                                                  float* __restrict__ rowsum) {
    __shared__ float red[256];
    const int b = blockIdx.x;
    const int c = blockIdx.y;                 // 4 chunks of 2000 float4
    const int t = threadIdx.x;
    const float4* row4 = (const float4*)(O + (size_t)b * VV);

    float s = 0.0f;
    for (int i = c * 2000 + t; i < (c + 1) * 2000; i += 256) {
        float4 f = row4[i];
        s += f.x + f.y + f.z + f.w;
    }
    red[t] = s;
    __syncthreads();
    for (int off = 128; off > 0; off >>= 1) {
        if (t < off) red[t] += red[t + off];
        __syncthreads();
    }
    if (t == 0) atomicAdd(&rowsum[b], red[0]);
}

// ---------------- K5c: normalize: out = exp_stored / rowsum[row] ---------------------
__global__ __launch_bounds__(256) void k5c_norm(float* __restrict__ O,
                                                const float* __restrict__ rowsum) {
    const int gid = blockIdx.x * 256 + threadIdx.x;      // 512000 float4's
    float4* O4 = (float4*)O;
    const u32 row = ((u32)gid * 4u) / (u32)VV;
    const float inv = fast_rcp(rowsum[row]);
    float4 f = O4[gid];
    f.x *= inv; f.y *= inv; f.z *= inv; f.w *= inv;
    O4[gid] = f;
}

extern "C" void kernel_launch(void* const* d_in, const int* in_sizes, int n_in,
                              void* d_out, int out_size, void* d_ws, size_t ws_size,
                              hipStream_t stream) {
    (void)in_sizes; (void)n_in; (void)out_size; (void)ws_size;
    const float* pcv       = (const float*)d_in[0];
    const float* F         = (const float*)d_in[1];
    const float* prev_char = (const float*)d_in[2];
    const float* state_h   = (const float*)d_in[3];
    const float* state_c   = (const float*)d_in[4];
    const float* Wc        = (const float*)d_in[5];
    const float* Wct1      = (const float*)d_in[6];
    const float* Wo        = (const float*)d_in[7];
    const float* Wct2      = (const float*)d_in[8];
    const float* lstm_k    = (const float*)d_in[9];
    const float* lstm_r    = (const float*)d_in[10];
    const float* W_h       = (const float*)d_in[11];
    const float* Vattn     = (const float*)d_in[12];

    // outputs: float32, concatenated flat in return order
    float* outO  = (float*)d_out;                  // [64][32000]
    float* outCt = outO + (size_t)BB * VV;         // [64][256]
    float* outH  = outCt + (size_t)BB * CHN;       // [64][128]
    float* outC  = outH + (size_t)BB * LL;         // [64][128]

    float* ws     = (float*)d_ws;
    float* part   = ws;                            // 250*4096 = 1,024,000 f
    float* pS     = part + (size_t)NC1 * BB * EE;  // 64*16*256 = 262,144 f
    float* pW     = pS + (size_t)BB * TS * CHN;    // 262,144 f
    float* At     = pW + (size_t)BB * TS * CHN;    // 384*64   = 24,576 f
    float* Htfm   = At + (LL + CHN) * BB;          // 16,384 f
    float* rowsum = part;                          // aliases dead part[0..63] after k2

    hipLaunchKernelGGL(k1_stage1, dim3(NC1, 2), dim3(256), 0, stream, prev_char, Wc, part);
    hipLaunchKernelGGL(k2_lstm, dim3(BB), dim3(512), 0, stream, part, pcv, state_h,
                       state_c, Wct1, lstm_k, lstm_r, W_h, outH, outC, At, Htfm);
    hipLaunchKernelGGL(k3_attn, dim3(BB, TS), dim3(256), 0, stream, F, Htfm, Vattn, pS, pW);
    hipLaunchKernelGGL(k4_combine, dim3(BB), dim3(256), 0, stream, pS, pW, outCt, At, rowsum);
    hipLaunchKernelGGL(k5_logits, dim3(NC1, 2), dim3(256), 0, stream, Wo, Wct2, At, outO);
    hipLaunchKernelGGL(k5b_expsum, dim3(BB, 4), dim3(256), 0, stream, outO, rowsum);
    hipLaunchKernelGGL(k5c_norm, dim3((BB * VV / 4) / 256), dim3(256), 0, stream, outO, rowsum);
}